// Round 2
// baseline (262.687 us; speedup 1.0000x reference)
//
#include <hip/hip_runtime.h>
#include <cstdint>

#define NH 6
#define HD 32
#define NTOK 256
#define CIN 576
#define DIMO 192
#define LOG2E 1.44269504f
#define SHIFT2 37.6f
#define MNEG (-144.269504f)   // -100 * log2(e)

typedef short short8 __attribute__((ext_vector_type(8)));
typedef float f32x4 __attribute__((ext_vector_type(4)));
typedef int   int4v __attribute__((ext_vector_type(4)));

__device__ __forceinline__ int grp6(int x) { return (x < 48) ? 0 : ((x < 56) ? 1 : 2); }

__device__ __forceinline__ unsigned short f2bf(float f) {
    unsigned int u = __float_as_uint(f);
    u += 0x7fffu + ((u >> 16) & 1u);   // RTNE
    return (unsigned short)(u >> 16);
}

// Tile-linear swizzled offset (in shorts) for the Q/K fragment buffers.
// byte = tile*1024 + row*64 + (quad ^ ((row>>1)&3))*16
// Reads (row=l15, per-lane quad) form a 64x16B bijection over the 1KiB tile
// -> conflict-free ds_read_b128. Writes spread 8 lanes/bank-slot (optimal).
__device__ __forceinline__ int qk_off(int tile, int row, int quad) {
    return tile * 512 + row * 32 + ((quad ^ ((row >> 1) & 3)) << 3);
}

// ---------------- kernel 1: CPB MLP (block per table point) ----------------
__global__ void cpb_kernel(const float* __restrict__ table,
                           const float* __restrict__ w1,
                           const float* __restrict__ b1,
                           const float* __restrict__ w2,
                           float* __restrict__ bv) {
    __shared__ float hid[512];
    int p = blockIdx.x;                 // 0..960
    float t0 = table[2 * p], t1 = table[2 * p + 1];
    int t = threadIdx.x;                // 256 threads
    for (int j = t; j < 512; j += 256) {
        float hv = fmaf(t0, w1[2 * j], fmaf(t1, w1[2 * j + 1], b1[j]));
        hid[j] = fmaxf(hv, 0.f);
    }
    __syncthreads();
    if (t < 192) {
        int h = t >> 5, l = t & 31;
        const float* w2h = w2 + h * 512;
        float acc = 0.f;
        for (int j = l; j < 512; j += 32) acc = fmaf(hid[j], w2h[j], acc);
        acc += __shfl_xor(acc, 1, 32);
        acc += __shfl_xor(acc, 2, 32);
        acc += __shfl_xor(acc, 4, 32);
        acc += __shfl_xor(acc, 8, 32);
        acc += __shfl_xor(acc, 16, 32);
        // fold -SHIFT2 into the bias grid
        if (l == 0) bv[h * 961 + p] = (16.f / (1.f + __expf(-acc))) * LOG2E - SHIFT2;
    }
}

// ---------------- kernel 2: MFMA attention ----------------
// block = one (window, head), 512 threads = 8 waves; wave w owns q-rows [w*32, w*32+32)
// Swapped QK^T (S^T = mfma(K,Q)): each lane's q-row is lane-local (q_c = l15),
// P transposed to the PV A-fragment IN REGISTERS via v_cvt_pk_bf16_f32 +
// v_permlane32_swap_b32 (no LDS P buffer). The induced key-slot permutation
// (bit-reversal of key-pair index within each 32-key chunk) is folded into
// the V LDS layout at staging time.
//
// Block swizzle: the 24 blocks of one (batch, window-row) group -- 4 windows x
// 6 heads, which together read a contiguous ~2.36 MB stripe of qkv (16 full
// image rows, all heads/streams) -- are given ids spaced 8 apart within one
// 192-id chunk, so they land on the SAME XCD under round-robin dispatch and
// stream contiguous DRAM ranges instead of 128-B scatters.
__global__ __launch_bounds__(512, 4) void attn_kernel(
    const float* __restrict__ qkv,
    const float* __restrict__ logit_scale,
    const float* __restrict__ bv,
    float* __restrict__ out)
{
    __shared__ __align__(16) short Qb[NTOK * HD];   // 16 KB  Q bf16, scale*log2e folded (tile-linear swizzled)
    __shared__ __align__(16) short Kb[NTOK * HD];   // 16 KB  K bf16 normalized (tile-linear swizzled)
    __shared__ __align__(16) short Vt[HD * 264];    // 16.9 KB V^T, stride 264, slot-permuted within 32-chunks
    __shared__ float Bv[961];                       // bias grid * log2e - SHIFT2

    const int t = threadIdx.x;

    // ---- XCD-locality swizzle: id = r8 + 8*(j24 + 24*g8), group gg = r8 + 8*g8
    const int id  = blockIdx.x;          // 0..1535
    const int r8  = id & 7, q3 = id >> 3;       // q3: 0..191
    const int j24 = q3 % 24, g8 = q3 / 24;      // j24: 0..23, g8: 0..7
    const int gg  = r8 + 8 * g8;                // 0..63 = b*4 + wh
    const int h   = j24 % 6, ww = j24 / 6;      // head, window-col
    const int wh  = gg & 3,  b  = gg >> 2;      // window-row, batch

    const float scale2 = __expf(fminf(logit_scale[h], 4.6051702f)) * LOG2E;

    for (int p = t; p < 961; p += 512) Bv[p] = bv[h * 961 + p];

    // ---- balanced staging: 2 threads per token.
    //   s=0: q (norm+scale) + v[0:16);  s=1: k (norm) + v[16:32)
    {
        const int n = t >> 1, s = t & 1;
        const int i = n >> 4, j = n & 15;            // tile, row-in-tile
        const int rr = (wh * 16 + i + 8) & 63;
        const int cc = (ww * 16 + j + 8) & 63;
        const float* base = qkv + ((long)(b * 4096 + rr * 64 + cc)) * CIN + h * HD;

        // q or k stream (32 floats)
        float xv[32];
        {
            const float4* p4 = (const float4*)(base + s * DIMO);
#pragma unroll
            for (int w = 0; w < 8; ++w) {
                float4 x = p4[w];
                xv[4 * w + 0] = x.x; xv[4 * w + 1] = x.y; xv[4 * w + 2] = x.z; xv[4 * w + 3] = x.w;
            }
        }
        // v half (16 floats)
        float vv[16];
        {
            const float4* v4 = (const float4*)(base + 2 * DIMO + s * 16);
#pragma unroll
            for (int w = 0; w < 4; ++w) {
                float4 x = v4[w];
                vv[4 * w + 0] = x.x; vv[4 * w + 1] = x.y; vv[4 * w + 2] = x.z; vv[4 * w + 3] = x.w;
            }
        }

        // norm with 4 accumulators for ILP
        float a0 = 0.f, a1 = 0.f, a2 = 0.f, a3 = 0.f;
#pragma unroll
        for (int d = 0; d < 8; ++d) {
            a0 = fmaf(xv[d],      xv[d],      a0);
            a1 = fmaf(xv[d + 8],  xv[d + 8],  a1);
            a2 = fmaf(xv[d + 16], xv[d + 16], a2);
            a3 = fmaf(xv[d + 24], xv[d + 24], a3);
        }
        float ssum = (a0 + a1) + (a2 + a3);
        float sc = (s ? 1.f : scale2) / fmaxf(sqrtf(ssum), 1e-12f);

        short* dst = s ? Kb : Qb;
#pragma unroll
        for (int w = 0; w < 4; ++w) {
            short8 xc;
#pragma unroll
            for (int e = 0; e < 8; ++e) xc[e] = (short)f2bf(xv[8 * w + e] * sc);
            *(short8*)&dst[qk_off(i, j, w)] = xc;
        }

        // V^T staging: col = chunk*32 + 2*brev4(pair) + (n&1)
        {
            int u = (n >> 1) & 15;
            int jp = ((u & 1) << 3) | ((u & 2) << 1) | ((u & 4) >> 1) | ((u & 8) >> 3);
            int col = (n >> 5) * 32 + 2 * jp + (n & 1);
#pragma unroll
            for (int di = 0; di < 16; ++di) {
                int e = (di + 4 * s) & 15;           // s=1 rotated by 4 rows: bank sets 16 apart
                Vt[(s * 16 + e) * 264 + col] = (short)f2bf(vv[e]);
            }
        }
    }
    __syncthreads();

    // ---- per-wave MFMA flash loop
    const int wv = t >> 6, lane = t & 63, quad = lane >> 4, l15 = lane & 15;

    int trg[2] = {wv * 2, wv * 2 + 1};
    short8 bQ[2];
#pragma unroll
    for (int tl = 0; tl < 2; ++tl)
        bQ[tl] = *(const short8*)&Qb[qk_off(trg[tl], l15, quad)];

    int gqr[2];
#pragma unroll
    for (int tl = 0; tl < 2; ++tl) gqr[tl] = grp6(wh * 16 + trg[tl]);
    const int gcl = grp6(ww * 16 + l15);        // q column-group: per-lane const
    float cm[4];
#pragma unroll
    for (int reg = 0; reg < 4; ++reg)
        cm[reg] = (gcl == grp6(ww * 16 + quad * 4 + reg)) ? 0.f : MNEG;

    f32x4 O[2][2];
    float lp[2] = {0.f, 0.f};
#pragma unroll
    for (int tl = 0; tl < 2; ++tl)
#pragma unroll
        for (int dtk = 0; dtk < 2; ++dtk) O[tl][dtk] = (f32x4){0.f, 0.f, 0.f, 0.f};

    const f32x4 Zero = (f32x4){0.f, 0.f, 0.f, 0.f};

    for (int c = 0; c < 8; ++c) {
        int ctg[2] = {2 * c, 2 * c + 1};
        short8 aK[2], bV[2];
#pragma unroll
        for (int ct = 0; ct < 2; ++ct)
            aK[ct] = *(const short8*)&Kb[qk_off(ctg[ct], l15, quad)];
#pragma unroll
        for (int dtk = 0; dtk < 2; ++dtk)
            bV[dtk] = *(const short8*)&Vt[(dtk * 16 + l15) * 264 + c * 32 + quad * 8];

        // S^T = K * Q^T : lane holds S^T[key=ctg*16+quad*4+reg][q=trg*16+l15]
        f32x4 S[2][2];
#pragma unroll
        for (int tl = 0; tl < 2; ++tl)
#pragma unroll
            for (int ct = 0; ct < 2; ++ct)
                S[tl][ct] = __builtin_amdgcn_mfma_f32_16x16x32_bf16(aK[ct], bQ[tl], Zero, 0, 0, 0);

        int gkr[2] = {grp6(wh * 16 + ctg[0]), grp6(wh * 16 + ctg[1])};

#pragma unroll
        for (int tl = 0; tl < 2; ++tl) {
            float ev[2][4];
#pragma unroll
            for (int ct = 0; ct < 2; ++ct) {
                int rb = (trg[tl] - ctg[ct] + 15) * 31 + 15 + l15 - 4 * quad;
                bool rmatch = (gqr[tl] == gkr[ct]);       // wave-uniform
#pragma unroll
                for (int reg = 0; reg < 4; ++reg) {
                    float madd = rmatch ? cm[reg] : MNEG;
                    float arg = S[tl][ct][reg] + (Bv[rb - reg] + madd);
                    float e = __builtin_amdgcn_exp2f(arg);
                    ev[ct][reg] = e;
                    lp[tl] += e;                          // row q = trg*16+l15
                }
            }
            // pack to bf16 pairs; key-pairs: P0=(ct0 r4q,r4q+1) P1=(ct1 ...) P2=(ct0 r4q+2,+3) P3=(ct1 ...)
            int p0, p1, p2, p3;
            asm("v_cvt_pk_bf16_f32 %0, %1, %2" : "=v"(p0) : "v"(ev[0][0]), "v"(ev[0][1]));
            asm("v_cvt_pk_bf16_f32 %0, %1, %2" : "=v"(p1) : "v"(ev[1][0]), "v"(ev[1][1]));
            asm("v_cvt_pk_bf16_f32 %0, %1, %2" : "=v"(p2) : "v"(ev[0][2]), "v"(ev[0][3]));
            asm("v_cvt_pk_bf16_f32 %0, %1, %2" : "=v"(p3) : "v"(ev[1][2]), "v"(ev[1][3]));
            // exchange halves: p0 <- [p0.lo, p2.lo-from-partner], p2 <- [p0.hi-from-partner, p2.hi]
            asm("v_permlane32_swap_b32 %0, %1" : "+v"(p0), "+v"(p2));
            asm("v_permlane32_swap_b32 %0, %1" : "+v"(p1), "+v"(p3));
            // A-fragment dwords [p0,p1,p2,p3]; key-slot->token map = brev4 of pair
            // index (same permutation baked into Vt staging above)
            int4v w = {p0, p1, p2, p3};
            union { int4v i; short8 s; } cvt; cvt.i = w;
            short8 aP = cvt.s;
            O[tl][0] = __builtin_amdgcn_mfma_f32_16x16x32_bf16(aP, bV[0], O[tl][0], 0, 0, 0);
            O[tl][1] = __builtin_amdgcn_mfma_f32_16x16x32_bf16(aP, bV[1], O[tl][1], 0, 0, 0);
        }
    }

    // ---- softmax denominator: reduce across quads, then gather per output row
    const long pixb = (long)b * 4096;
#pragma unroll
    for (int tl = 0; tl < 2; ++tl) {
        float s = lp[tl];
        s += __shfl_xor(s, 16);
        s += __shfl_xor(s, 32);
        float invf = 1.f / s;                     // for q = trg*16 + l15
        int r = (wh * 16 + trg[tl] + 8) & 63;
#pragma unroll
        for (int reg = 0; reg < 4; ++reg) {
            float iv = __shfl(invf, quad * 4 + reg);   // row-sum for q = trg*16 + quad*4+reg
            int cpix = (ww * 16 + quad * 4 + reg + 8) & 63;
            float* op = out + (pixb + r * 64 + cpix) * DIMO + h * HD + l15;
            op[0]  = O[tl][0][reg] * iv;
            op[16] = O[tl][1][reg] * iv;
        }
    }
}

extern "C" void kernel_launch(void* const* d_in, const int* in_sizes, int n_in,
                              void* d_out, int out_size, void* d_ws, size_t ws_size,
                              hipStream_t stream) {
    const float* qkv         = (const float*)d_in[0];
    const float* table       = (const float*)d_in[1];
    // d_in[2] = mask   : recomputed from window-region groups
    const float* logit_scale = (const float*)d_in[3];
    const float* w1          = (const float*)d_in[4];
    const float* b1          = (const float*)d_in[5];
    const float* w2          = (const float*)d_in[6];
    // d_in[7] = index  : recomputed from relative coords
    float* out = (float*)d_out;
    float* bv  = (float*)d_ws;   // 6*961 floats

    cpb_kernel<<<961, 256, 0, stream>>>(table, w1, b1, w2, bv);
    attn_kernel<<<256 * NH, 512, 0, stream>>>(qkv, logit_scale, bv, out);
}